// Round 3
// baseline (15421.973 us; speedup 1.0000x reference)
//
#include <hip/hip_runtime.h>
#include <hip/hip_bf16.h>

constexpr int B   = 4;
constexpr int N   = 1024;
constexpr int D   = 128;
constexpr int KNN = 10;
constexpr int NH  = 4;

// ---------------------------------------------------------------- norm p2d
__global__ __launch_bounds__(256) void k_norm2d(const float* __restrict__ p2d,
                                                float* __restrict__ f2) {
  int i = blockIdx.x * 256 + threadIdx.x;  // over B*N
  const float* p = p2d + (size_t)i * 3;
  float x = p[0], y = p[1], z = p[2];
  float inr = 1.f / sqrtf(x * x + y * y + z * z);
  float* o = f2 + (size_t)i * 3;
  o[0] = x * inr; o[1] = y * inr; o[2] = z * inr;
}

// ---------------------------------------------------------------- KNN encode
__global__ __launch_bounds__(256) void k_encode(const float* __restrict__ pts,
                                                const float* __restrict__ w,
                                                const float* __restrict__ bias,
                                                float* __restrict__ desc) {
  __shared__ float P[N][3];
  __shared__ float xx[N];
  __shared__ float dist[N];
  __shared__ float rv[256];
  __shared__ int   ri[256];
  __shared__ float feat[6];
  __shared__ int   nidx[KNN];
  int t = threadIdx.x;
  int n = blockIdx.x, b = blockIdx.y;
  const float* pb = pts + (size_t)b * N * 3;
  for (int i = t; i < N; i += 256) {
    float x = pb[i * 3 + 0], y = pb[i * 3 + 1], z = pb[i * 3 + 2];
    P[i][0] = x; P[i][1] = y; P[i][2] = z;
    xx[i] = x * x + y * y + z * z;
  }
  __syncthreads();
  float cx = P[n][0], cy = P[n][1], cz = P[n][2], cxx = xx[n];
  for (int i = t; i < N; i += 256) {
    float ip = cx * P[i][0] + cy * P[i][1] + cz * P[i][2];
    dist[i] = 2.f * ip - cxx - xx[i];
  }
  __syncthreads();
  for (int kk = 0; kk < KNN; ++kk) {
    float bv = -3.0e38f; int bi = N;
    for (int i = t; i < N; i += 256) {
      float v = dist[i];
      if (v > bv) { bv = v; bi = i; }
    }
    rv[t] = bv; ri[t] = bi;
    __syncthreads();
    for (int s = 128; s > 0; s >>= 1) {
      if (t < s) {
        float v2 = rv[t + s]; int i2 = ri[t + s];
        if (v2 > rv[t] || (v2 == rv[t] && i2 < ri[t])) { rv[t] = v2; ri[t] = i2; }
      }
      __syncthreads();
    }
    if (t == 0) { nidx[kk] = ri[0]; dist[ri[0]] = -3.0e38f; }
    __syncthreads();
  }
  if (t == 0) {
    float sx = 0, sy = 0, sz = 0;
    for (int kk = 0; kk < KNN; ++kk) {
      int i = nidx[kk];
      sx += P[i][0]; sy += P[i][1]; sz += P[i][2];
    }
    const float invk = 1.f / KNN;
    feat[0] = sx * invk - cx; feat[1] = sy * invk - cy; feat[2] = sz * invk - cz;
    feat[3] = cx; feat[4] = cy; feat[5] = cz;
  }
  __syncthreads();
  if (t < D) {
    const float* wr = w + t * 6;
    float a = bias[t];
#pragma unroll
    for (int j = 0; j < 6; ++j) a += wr[j] * feat[j];
    desc[((size_t)b * D + t) * N + n] = a;
  }
}

// ---------------------------------------------------------------- generic conv1 (8-o unroll)
// grid (N/256, Cout/8, 2*B)
__global__ __launch_bounds__(256) void k_conv(const float* __restrict__ in0,
                                              const float* __restrict__ in1,
                                              const float* __restrict__ cat0,
                                              const float* __restrict__ cat1,
                                              const float* __restrict__ w,
                                              const float* __restrict__ bias,
                                              const float* __restrict__ res,
                                              float* __restrict__ out,
                                              int Cin, int catOff,
                                              size_t in_bstr, size_t cat_bstr,
                                              int Cout) {
  int n = blockIdx.x * 256 + threadIdx.x;
  int o0 = blockIdx.y * 8;
  int z = blockIdx.z;           // s*B + b
  int s = z >> 2, b = z & 3;
  const float* ip = (s ? in1 : in0) + (size_t)b * in_bstr;
  const float* w0 = w + (size_t)o0 * Cin;
  float a[8];
#pragma unroll
  for (int i = 0; i < 8; ++i) a[i] = bias[o0 + i];
#pragma unroll 2
  for (int c = 0; c < catOff; ++c) {
    float v = ip[(size_t)c * N + n];
#pragma unroll
    for (int i = 0; i < 8; ++i) a[i] = fmaf(w0[i * Cin + c], v, a[i]);
  }
  if (cat0) {
    const float* cp = (s ? cat1 : cat0) + (size_t)b * cat_bstr;
#pragma unroll 2
    for (int c = catOff; c < Cin; ++c) {
      float v = cp[(size_t)(c - catOff) * N + n];
#pragma unroll
      for (int i = 0; i < 8; ++i) a[i] = fmaf(w0[i * Cin + c], v, a[i]);
    }
  }
  size_t ob = ((size_t)z * Cout + o0) * N + n;
  if (res) {
#pragma unroll
    for (int i = 0; i < 8; ++i) a[i] += res[ob + (size_t)i * N];
  }
#pragma unroll
  for (int i = 0; i < 8; ++i) out[ob + (size_t)i * N] = a[i];
}

// ---------------------------------------------------------------- attention v3
// grid (N/128, NH, 2*B), 256 thr = 4 waves. Wave s owns keys [s*256,(s+1)*256).
// Each lane owns TWO queries (lq and lq+64 within the block's 128). K/V chunks
// of 32 keys staged per-wave (linear [64 rows][32] layout -> conflict-free
// contiguous writes), double-buffered, NO barriers in the K-loop (wave-local
// LDS ordering). Broadcast ds_read_b128 feeds 8 FMAs (4 keys x 2 queries).
__global__ __launch_bounds__(256, 1) void k_attn(const float* __restrict__ Q,
                                                 const float* __restrict__ Kt,
                                                 const float* __restrict__ Vt,
                                                 float* __restrict__ O) {
  __shared__ float pool[16896];          // staging 4*4096; merge 4*128*33
  __shared__ float ms_[4][128], ls_[4][128];
  const int t  = threadIdx.x;
  const int lq = t & 63, s = t >> 6;
  const int q0 = blockIdx.x * 128;
  const int h  = blockIdx.y;
  const int z  = blockIdx.z;
  const size_t base = (size_t)z * (size_t)(D * N);
  const float* Kb = Kt + base;
  const float* Vb = Vt + base;
  const int stageBase = s * 4096;
  const int wrow  = lq >> 3;            // 0..7
  const int wslot = (lq & 7) * 4;       // 0,4,..28

  float qA[32], qB[32], accA[32], accB[32];
#pragma unroll
  for (int d = 0; d < 32; ++d) {
    qA[d] = Q[base + (size_t)(d * 4 + h) * N + q0 + lq];
    qB[d] = Q[base + (size_t)(d * 4 + h) * N + q0 + 64 + lq];
    accA[d] = 0.f; accB[d] = 0.f;
  }
  float mxA = -1e30f, mxB = -1e30f, lA = 0.f, lB = 0.f;
  const float scale = 0.17677669529663687f;  // 1/sqrt(32)

  // stage chunk 0
  {
    int k0 = s * 256;
#pragma unroll
    for (int it = 0; it < 8; ++it) {
      int row = it * 8 + wrow;
      const float* src = (row < 32) ? (Kb + (size_t)(row * 4 + h) * N)
                                    : (Vb + (size_t)((row - 32) * 4 + h) * N);
      float4 g = *(const float4*)(src + k0 + wslot);
      *(float4*)&pool[stageBase + row * 32 + wslot] = g;
    }
  }

  for (int c = 0; c < 8; ++c) {
    // prefetch next chunk into regs
    float4 g[8];
    if (c < 7) {
      int k0 = s * 256 + (c + 1) * 32;
#pragma unroll
      for (int it = 0; it < 8; ++it) {
        int row = it * 8 + wrow;
        const float* src = (row < 32) ? (Kb + (size_t)(row * 4 + h) * N)
                                      : (Vb + (size_t)((row - 32) * 4 + h) * N);
        g[it] = *(const float4*)(src + k0 + wslot);
      }
    }
    const int sb = stageBase + (c & 1) * 2048;
#pragma unroll
    for (int half = 0; half < 2; ++half) {
      float scA[16], scB[16];
#pragma unroll
      for (int jg = 0; jg < 4; ++jg) {
        int j0 = half * 16 + jg * 4;
        float a0 = 0, a1 = 0, a2 = 0, a3 = 0, b0 = 0, b1 = 0, b2 = 0, b3 = 0;
#pragma unroll
        for (int d = 0; d < 32; ++d) {
          const float4 kv = *(const float4*)&pool[sb + d * 32 + j0];
          a0 = fmaf(qA[d], kv.x, a0); a1 = fmaf(qA[d], kv.y, a1);
          a2 = fmaf(qA[d], kv.z, a2); a3 = fmaf(qA[d], kv.w, a3);
          b0 = fmaf(qB[d], kv.x, b0); b1 = fmaf(qB[d], kv.y, b1);
          b2 = fmaf(qB[d], kv.z, b2); b3 = fmaf(qB[d], kv.w, b3);
        }
        scA[jg * 4 + 0] = a0 * scale; scA[jg * 4 + 1] = a1 * scale;
        scA[jg * 4 + 2] = a2 * scale; scA[jg * 4 + 3] = a3 * scale;
        scB[jg * 4 + 0] = b0 * scale; scB[jg * 4 + 1] = b1 * scale;
        scB[jg * 4 + 2] = b2 * scale; scB[jg * 4 + 3] = b3 * scale;
      }
      // online softmax over these 16 keys
      float hA = scA[0], hB = scB[0];
#pragma unroll
      for (int j = 1; j < 16; ++j) { hA = fmaxf(hA, scA[j]); hB = fmaxf(hB, scB[j]); }
      float nmA = fmaxf(mxA, hA), nmB = fmaxf(mxB, hB);
      float cA = __expf(mxA - nmA), cB = __expf(mxB - nmB);
      lA *= cA; lB *= cB;
#pragma unroll
      for (int d = 0; d < 32; ++d) { accA[d] *= cA; accB[d] *= cB; }
      mxA = nmA; mxB = nmB;
#pragma unroll
      for (int j = 0; j < 16; ++j) {
        scA[j] = __expf(scA[j] - mxA); lA += scA[j];
        scB[j] = __expf(scB[j] - mxB); lB += scB[j];
      }
      // PV
#pragma unroll
      for (int jg = 0; jg < 4; ++jg) {
        int j0 = half * 16 + jg * 4;
        float pa0 = scA[jg * 4 + 0], pa1 = scA[jg * 4 + 1];
        float pa2 = scA[jg * 4 + 2], pa3 = scA[jg * 4 + 3];
        float pb0 = scB[jg * 4 + 0], pb1 = scB[jg * 4 + 1];
        float pb2 = scB[jg * 4 + 2], pb3 = scB[jg * 4 + 3];
#pragma unroll
        for (int d = 0; d < 32; ++d) {
          const float4 v = *(const float4*)&pool[sb + (32 + d) * 32 + j0];
          accA[d] = fmaf(pa0, v.x, fmaf(pa1, v.y, fmaf(pa2, v.z, fmaf(pa3, v.w, accA[d]))));
          accB[d] = fmaf(pb0, v.x, fmaf(pb1, v.y, fmaf(pb2, v.z, fmaf(pb3, v.w, accB[d]))));
        }
      }
    }
    // write prefetched chunk to the other buffer
    if (c < 7) {
      const int db = stageBase + ((c + 1) & 1) * 2048;
#pragma unroll
      for (int it = 0; it < 8; ++it) {
        int row = it * 8 + wrow;
        *(float4*)&pool[db + row * 32 + wslot] = g[it];
      }
    }
  }

  // ---- merge 4 key-split partials
  ms_[s][lq] = mxA; ms_[s][64 + lq] = mxB;
  ls_[s][lq] = lA;  ls_[s][64 + lq] = lB;
  __syncthreads();                       // all staging reads done
#pragma unroll
  for (int d = 0; d < 32; ++d) {
    pool[(s * 128 + lq) * 33 + d] = accA[d];
    pool[(s * 128 + 64 + lq) * 33 + d] = accB[d];
  }
  __syncthreads();
  {
    int qq = t & 127, dh = t >> 7;
    float M = fmaxf(fmaxf(ms_[0][qq], ms_[1][qq]), fmaxf(ms_[2][qq], ms_[3][qq]));
    float wg[4], L = 0.f;
#pragma unroll
    for (int ss = 0; ss < 4; ++ss) {
      wg[ss] = __expf(ms_[ss][qq] - M);
      L += ls_[ss][qq] * wg[ss];
    }
    float invL = 1.f / L;
#pragma unroll
    for (int k = 0; k < 16; ++k) {
      int d = dh * 16 + k;
      float o = 0.f;
#pragma unroll
      for (int ss = 0; ss < 4; ++ss) o += pool[(ss * 128 + qq) * 33 + d] * wg[ss];
      O[base + (size_t)(d * 4 + h) * N + q0 + qq] = o * invL;
    }
  }
}

// ---------------------------------------------------------------- BN stats
__global__ __launch_bounds__(256) void k_bnstat(const float* __restrict__ h,
                                                float* __restrict__ stat) {
  int c = blockIdx.x, s = blockIdx.y, t = threadIdx.x;
  __shared__ float red[256];
  const float* base = h + ((size_t)s * B * 256 + c) * N;
  float sum = 0;
  for (int b = 0; b < B; ++b)
    for (int i = t; i < N; i += 256) sum += base[(size_t)b * 256 * N + i];
  red[t] = sum; __syncthreads();
  for (int sft = 128; sft > 0; sft >>= 1) {
    if (t < sft) red[t] += red[t + sft];
    __syncthreads();
  }
  float mean = red[0] / (float)(B * N);
  __syncthreads();
  float vs = 0;
  for (int b = 0; b < B; ++b)
    for (int i = t; i < N; i += 256) {
      float d = base[(size_t)b * 256 * N + i] - mean;
      vs += d * d;
    }
  red[t] = vs; __syncthreads();
  for (int sft = 128; sft > 0; sft >>= 1) {
    if (t < sft) red[t] += red[t + sft];
    __syncthreads();
  }
  if (t == 0) {
    float var = red[0] / (float)(B * N);
    stat[(s * 256 + c) * 2 + 0] = mean;
    stat[(s * 256 + c) * 2 + 1] = 1.f / sqrtf(var + 1e-5f);
  }
}

// ---------------------------------------------------------------- BN apply + relu
__global__ __launch_bounds__(256) void k_bnrelu(float* __restrict__ h,
                                                const float* __restrict__ stat,
                                                const float* __restrict__ g,
                                                const float* __restrict__ bt) {
  int i = blockIdx.x * 256 + threadIdx.x;
  int c = (i / N) % 256;
  int s = i / (B * 256 * N);
  float m = stat[(s * 256 + c) * 2 + 0];
  float is = stat[(s * 256 + c) * 2 + 1];
  float v = (h[i] - m) * is * g[c] + bt[c];
  h[i] = v > 0.f ? v : 0.f;
}

// ---------------------------------------------------------------- pairwise dist (8-m tile)
__global__ __launch_bounds__(256) void k_dist(const float* __restrict__ d0,
                                              const float* __restrict__ d1,
                                              float* __restrict__ la) {
  __shared__ float xm[8][128];
  __shared__ float n0s[8];
  int m0 = blockIdx.x * 8, b = blockIdx.y, t = threadIdx.x;
  const float* p0 = d0 + (size_t)b * D * N;
  const float* p1 = d1 + (size_t)b * D * N;
  for (int i = t; i < 8 * 128; i += 256) {
    int mm = i >> 7, d = i & 127;
    xm[mm][d] = p0[(size_t)d * N + m0 + mm];
  }
  __syncthreads();
  if (t < 8) {
    float s = 0;
    for (int d = 0; d < 128; ++d) s += xm[t][d] * xm[t][d];
    n0s[t] = s;
  }
  __syncthreads();
  float dot[8][4] = {{0}};
  float n1[4] = {0, 0, 0, 0};
  for (int d = 0; d < 128; ++d) {
    float v[4];
#pragma unroll
    for (int u = 0; u < 4; ++u) {
      v[u] = p1[(size_t)d * N + t + u * 256];
      n1[u] = fmaf(v[u], v[u], n1[u]);
    }
#pragma unroll
    for (int mm = 0; mm < 8; ++mm) {
      float x = xm[mm][d];
#pragma unroll
      for (int u = 0; u < 4; ++u) dot[mm][u] = fmaf(x, v[u], dot[mm][u]);
    }
  }
  for (int mm = 0; mm < 8; ++mm) {
    float* row = la + ((size_t)b * N + m0 + mm) * N;
#pragma unroll
    for (int u = 0; u < 4; ++u) {
      float dist2 = fmaxf(n0s[mm] + n1[u] - 2.f * dot[mm][u], 1e-30f);
      row[t + u * 256] = -sqrtf(dist2);
    }
  }
}

// ---------------------------------------------------------------- sinkhorn row (+ pending col sub)
__global__ __launch_bounds__(256) void k_row_lse(float* __restrict__ la,
                                                 const float* __restrict__ colse) {
  __shared__ float red[256];
  int t = threadIdx.x;
  int bm = blockIdx.x;              // over B*N
  int b = bm >> 10;
  float* row = la + (size_t)bm * N;
  float v0 = row[t], v1 = row[t + 256], v2 = row[t + 512], v3 = row[t + 768];
  if (colse) {
    const float* cl = colse + (size_t)b * N;
    v0 -= cl[t]; v1 -= cl[t + 256]; v2 -= cl[t + 512]; v3 -= cl[t + 768];
  }
  float mx = fmaxf(fmaxf(v0, v1), fmaxf(v2, v3));
  red[t] = mx; __syncthreads();
  for (int s = 128; s > 0; s >>= 1) {
    if (t < s) red[t] = fmaxf(red[t], red[t + s]);
    __syncthreads();
  }
  mx = red[0]; __syncthreads();
  float se = __expf(v0 - mx) + __expf(v1 - mx) + __expf(v2 - mx) + __expf(v3 - mx);
  red[t] = se; __syncthreads();
  for (int s = 128; s > 0; s >>= 1) {
    if (t < s) red[t] += red[t + s];
    __syncthreads();
  }
  float lse = mx + __logf(red[0]);
  row[t] = v0 - lse; row[t + 256] = v1 - lse;
  row[t + 512] = v2 - lse; row[t + 768] = v3 - lse;
}

// ---------------------------------------------------------------- sinkhorn col
__global__ __launch_bounds__(256) void k_col_part(const float* __restrict__ la,
                                                  float* __restrict__ pmax,
                                                  float* __restrict__ psum) {
  int t = threadIdx.x;
  int n = blockIdx.x * 256 + t;
  int p = blockIdx.y, b = blockIdx.z;
  const float* base = la + ((size_t)b * N + p * 128) * N + n;
  float mx = -1e30f, s = 0;
  for (int m = 0; m < 128; ++m) {
    float v = base[(size_t)m * N];
    if (v > mx) { s = s * __expf(mx - v) + 1.f; mx = v; }
    else s += __expf(v - mx);
  }
  pmax[((size_t)b * 8 + p) * N + n] = mx;
  psum[((size_t)b * 8 + p) * N + n] = s;
}

__global__ __launch_bounds__(256) void k_col_fin(const float* __restrict__ pmax,
                                                 const float* __restrict__ psum,
                                                 float* __restrict__ lse) {
  int i = blockIdx.x * 256 + threadIdx.x;  // over B*N
  int b = i / N, n = i % N;
  float mx = -1e30f;
  for (int p = 0; p < 8; ++p) mx = fmaxf(mx, pmax[((size_t)b * 8 + p) * N + n]);
  float s = 0;
  for (int p = 0; p < 8; ++p)
    s += psum[((size_t)b * 8 + p) * N + n] * __expf(pmax[((size_t)b * 8 + p) * N + n] - mx);
  lse[i] = mx + __logf(s);
}

// ---------------------------------------------------------------- rodrigues + transform
__global__ __launch_bounds__(256) void k_rod(const float* __restrict__ pose,
                                             const float* __restrict__ p3d,
                                             float* __restrict__ p3dt) {
  int b = blockIdx.y;
  int n = blockIdx.x * 256 + threadIdx.x;
  const float* aa = pose + b * 6;
  float ax = aa[0], ay = aa[1], az = aa[2];
  float th = fmaxf(sqrtf(ax * ax + ay * ay + az * az), 1e-8f);
  float rx = ax / th, ry = ay / th, rz = az / th;
  float c = cosf(th), s = sinf(th), oc = 1.f - c;
  float R00 = c + oc * rx * rx,      R01 = oc * rx * ry - s * rz, R02 = oc * rx * rz + s * ry;
  float R10 = oc * ry * rx + s * rz, R11 = c + oc * ry * ry,      R12 = oc * ry * rz - s * rx;
  float R20 = oc * rz * rx - s * ry, R21 = oc * rz * ry + s * rx, R22 = c + oc * rz * rz;
  const float* p = p3d + ((size_t)b * N + n) * 3;
  float x = p[0], y = p[1], z = p[2];
  float X = R00 * x + R01 * y + R02 * z + aa[3];
  float Y = R10 * x + R11 * y + R12 * z + aa[4];
  float Z = R20 * x + R21 * y + R22 * z + aa[5];
  float inr = 1.f / sqrtf(X * X + Y * Y + Z * Z);
  float* o = p3dt + ((size_t)b * N + n) * 3;
  o[0] = X * inr; o[1] = Y * inr; o[2] = Z * inr;
}

// ---------------------------------------------------------------- final error
__global__ __launch_bounds__(256) void k_err(const float* __restrict__ la,
                                             const float* __restrict__ colse,
                                             const float* __restrict__ f2,
                                             const float* __restrict__ p3dt,
                                             float* __restrict__ rowsum) {
  __shared__ float red[256];
  int m = blockIdx.x, b = blockIdx.y, t = threadIdx.x;
  const float* row = la + ((size_t)b * N + m) * N;
  const float* cl = colse + (size_t)b * N;
  const float* f = f2 + ((size_t)b * N + m) * 3;
  float fx = f[0], fy = f[1], fz = f[2];
  float s = 0;
  for (int n = t; n < N; n += 256) {
    const float* pp = p3dt + ((size_t)b * N + n) * 3;
    float dot = fx * pp[0] + fy * pp[1] + fz * pp[2];
    s += __expf(row[n] - cl[n]) * (1.f - dot);
  }
  red[t] = s; __syncthreads();
  for (int sft = 128; sft > 0; sft >>= 1) {
    if (t < sft) red[t] += red[t + sft];
    __syncthreads();
  }
  if (t == 0) rowsum[(size_t)b * N + m] = red[0];
}

__global__ __launch_bounds__(256) void k_err_fin(const float* __restrict__ rowsum,
                                                 float* __restrict__ out) {
  __shared__ float red[256];
  int b = blockIdx.x, t = threadIdx.x;
  float s = 0;
  for (int i = t; i < N; i += 256) s += rowsum[(size_t)b * N + i];
  red[t] = s; __syncthreads();
  for (int sft = 128; sft > 0; sft >>= 1) {
    if (t < sft) red[t] += red[t + sft];
    __syncthreads();
  }
  if (t == 0) out[b] = red[0];
}

// ================================================================= host
extern "C" void kernel_launch(void* const* d_in, const int* in_sizes, int n_in,
                              void* d_out, int out_size, void* d_ws, size_t ws_size,
                              hipStream_t stream) {
  const float* p2d     = (const float*)d_in[0];
  const float* p3d     = (const float*)d_in[1];
  const float* pose    = (const float*)d_in[2];
  const float* enc2d_w = (const float*)d_in[3];
  const float* enc2d_b = (const float*)d_in[4];
  const float* enc3d_w = (const float*)d_in[5];
  const float* enc3d_b = (const float*)d_in[6];
  const float* proj_w  = (const float*)d_in[7];
  const float* proj_b  = (const float*)d_in[8];
  const float* merge_w = (const float*)d_in[9];
  const float* merge_b = (const float*)d_in[10];
  const float* mlp1_w  = (const float*)d_in[11];
  const float* mlp1_b  = (const float*)d_in[12];
  const float* bn_g    = (const float*)d_in[13];
  const float* bn_b    = (const float*)d_in[14];
  const float* mlp2_w  = (const float*)d_in[15];
  const float* mlp2_b  = (const float*)d_in[16];

  float* W = (float*)d_ws;
  size_t off = 0;
  auto alloc = [&](size_t nelem) { float* p = W + off; off += nelem; return p; };
  const size_t SET = (size_t)B * D * N;
  float* f2    = alloc((size_t)B * N * 3);
  float* p3dt  = alloc((size_t)B * N * 3);
  float* descA = alloc(2 * SET);
  float* descB = alloc(2 * SET);
  float* Qb    = alloc(2 * SET);
  float* Kb    = alloc(2 * SET);
  float* Vb    = alloc(2 * SET);
  float* attnb = alloc(2 * SET);
  float* msgb  = alloc(2 * SET);
  float* hb    = alloc((size_t)2 * B * 256 * N);
  float* stat  = alloc(2 * 256 * 2);
  float* la    = alloc((size_t)B * N * N);
  float* pmax  = alloc((size_t)B * 8 * N);
  float* psum  = alloc((size_t)B * 8 * N);
  float* lseb  = alloc((size_t)B * N);
  float* rowsum= alloc((size_t)B * N);
  (void)ws_size; (void)in_sizes; (void)n_in; (void)out_size;

  auto conv = [&](const float* in0, const float* in1, const float* cat0,
                  const float* cat1, const float* w, const float* bias,
                  const float* res, float* out, int Cin, int catOff,
                  size_t in_bstr, size_t cat_bstr, int Cout) {
    dim3 g(N / 256, Cout / 8, 2 * B);
    k_conv<<<g, 256, 0, stream>>>(in0, in1, cat0, cat1, w, bias, res, out,
                                  Cin, catOff, in_bstr, cat_bstr, Cout);
  };

  k_norm2d<<<(B * N) / 256, 256, 0, stream>>>(p2d, f2);
  k_encode<<<dim3(N, B), 256, 0, stream>>>(f2, enc2d_w, enc2d_b, descA);
  k_encode<<<dim3(N, B), 256, 0, stream>>>(p3d, enc3d_w, enc3d_b, descA + SET);

  float* dc = descA;
  float* dn = descB;
  for (int i = 0; i < 6; ++i) {
    bool cross = (i & 1);
    const float* pw = proj_w + (size_t)i * 3 * D * D;
    const float* pb = proj_b + (size_t)i * 3 * D;
    float* d0 = dc;
    float* d1 = dc + SET;
    const float* sA = cross ? d1 : d0;
    const float* sB = cross ? d0 : d1;
    conv(d0, d1, nullptr, nullptr, pw,             pb,         nullptr, Qb, D, D, (size_t)D * N, 0, D);
    conv(sA, sB, nullptr, nullptr, pw + D * D,     pb + D,     nullptr, Kb, D, D, (size_t)D * N, 0, D);
    conv(sA, sB, nullptr, nullptr, pw + 2 * D * D, pb + 2 * D, nullptr, Vb, D, D, (size_t)D * N, 0, D);
    k_attn<<<dim3(N / 128, NH, 2 * B), 256, 0, stream>>>(Qb, Kb, Vb, attnb);
    conv(attnb, attnb + SET, nullptr, nullptr, merge_w + (size_t)i * D * D,
         merge_b + (size_t)i * D, nullptr, msgb, D, D, (size_t)D * N, 0, D);
    conv(d0, d1, msgb, msgb + SET, mlp1_w + (size_t)i * 256 * 256,
         mlp1_b + (size_t)i * 256, nullptr, hb, 256, 128, (size_t)D * N,
         (size_t)D * N, 256);
    k_bnstat<<<dim3(256, 2), 256, 0, stream>>>(hb, stat);
    k_bnrelu<<<(2 * B * 256 * N) / 256, 256, 0, stream>>>(
        hb, stat, bn_g + (size_t)i * 256, bn_b + (size_t)i * 256);
    conv(hb, hb + (size_t)B * 256 * N, nullptr, nullptr,
         mlp2_w + (size_t)i * D * 256, mlp2_b + (size_t)i * D, dc, dn, 256, 256,
         (size_t)256 * N, 0, D);
    float* tmp = dc; dc = dn; dn = tmp;
  }

  k_dist<<<dim3(N / 8, B), 256, 0, stream>>>(dc, dc + SET, la);
  for (int it = 0; it < 10; ++it) {
    k_row_lse<<<B * N, 256, 0, stream>>>(la, it == 0 ? nullptr : lseb);
    k_col_part<<<dim3(N / 256, 8, B), 256, 0, stream>>>(la, pmax, psum);
    k_col_fin<<<(B * N) / 256, 256, 0, stream>>>(pmax, psum, lseb);
  }
  k_rod<<<dim3(N / 256, B), 256, 0, stream>>>(pose, p3d, p3dt);
  k_err<<<dim3(N, B), 256, 0, stream>>>(la, lseb, f2, p3dt, rowsum);
  k_err_fin<<<B, 256, 0, stream>>>(rowsum, (float*)d_out);
}

// Round 4
// 4727.628 us; speedup vs baseline: 3.2621x; 3.2621x over previous
//
#include <hip/hip_runtime.h>
#include <hip/hip_bf16.h>

constexpr int B   = 4;
constexpr int N   = 1024;
constexpr int D   = 128;
constexpr int KNN = 10;
constexpr int NH  = 4;

// ---------------------------------------------------------------- norm p2d
__global__ __launch_bounds__(256) void k_norm2d(const float* __restrict__ p2d,
                                                float* __restrict__ f2) {
  int i = blockIdx.x * 256 + threadIdx.x;  // over B*N
  const float* p = p2d + (size_t)i * 3;
  float x = p[0], y = p[1], z = p[2];
  float inr = 1.f / sqrtf(x * x + y * y + z * z);
  float* o = f2 + (size_t)i * 3;
  o[0] = x * inr; o[1] = y * inr; o[2] = z * inr;
}

// ---------------------------------------------------------------- KNN encode
__global__ __launch_bounds__(256) void k_encode(const float* __restrict__ pts,
                                                const float* __restrict__ w,
                                                const float* __restrict__ bias,
                                                float* __restrict__ desc) {
  __shared__ float P[N][3];
  __shared__ float xx[N];
  __shared__ float dist[N];
  __shared__ float rv[256];
  __shared__ int   ri[256];
  __shared__ float feat[6];
  __shared__ int   nidx[KNN];
  int t = threadIdx.x;
  int n = blockIdx.x, b = blockIdx.y;
  const float* pb = pts + (size_t)b * N * 3;
  for (int i = t; i < N; i += 256) {
    float x = pb[i * 3 + 0], y = pb[i * 3 + 1], z = pb[i * 3 + 2];
    P[i][0] = x; P[i][1] = y; P[i][2] = z;
    xx[i] = x * x + y * y + z * z;
  }
  __syncthreads();
  float cx = P[n][0], cy = P[n][1], cz = P[n][2], cxx = xx[n];
  for (int i = t; i < N; i += 256) {
    float ip = cx * P[i][0] + cy * P[i][1] + cz * P[i][2];
    dist[i] = 2.f * ip - cxx - xx[i];
  }
  __syncthreads();
  for (int kk = 0; kk < KNN; ++kk) {
    float bv = -3.0e38f; int bi = N;
    for (int i = t; i < N; i += 256) {
      float v = dist[i];
      if (v > bv) { bv = v; bi = i; }
    }
    rv[t] = bv; ri[t] = bi;
    __syncthreads();
    for (int s = 128; s > 0; s >>= 1) {
      if (t < s) {
        float v2 = rv[t + s]; int i2 = ri[t + s];
        if (v2 > rv[t] || (v2 == rv[t] && i2 < ri[t])) { rv[t] = v2; ri[t] = i2; }
      }
      __syncthreads();
    }
    if (t == 0) { nidx[kk] = ri[0]; dist[ri[0]] = -3.0e38f; }
    __syncthreads();
  }
  if (t == 0) {
    float sx = 0, sy = 0, sz = 0;
    for (int kk = 0; kk < KNN; ++kk) {
      int i = nidx[kk];
      sx += P[i][0]; sy += P[i][1]; sz += P[i][2];
    }
    const float invk = 1.f / KNN;
    feat[0] = sx * invk - cx; feat[1] = sy * invk - cy; feat[2] = sz * invk - cz;
    feat[3] = cx; feat[4] = cy; feat[5] = cz;
  }
  __syncthreads();
  if (t < D) {
    const float* wr = w + t * 6;
    float a = bias[t];
#pragma unroll
    for (int j = 0; j < 6; ++j) a += wr[j] * feat[j];
    desc[((size_t)b * D + t) * N + n] = a;
  }
}

// ---------------------------------------------------------------- generic conv1 (8-o unroll)
// grid (N/256, Cout/8, 2*B)
__global__ __launch_bounds__(256) void k_conv(const float* __restrict__ in0,
                                              const float* __restrict__ in1,
                                              const float* __restrict__ cat0,
                                              const float* __restrict__ cat1,
                                              const float* __restrict__ w,
                                              const float* __restrict__ bias,
                                              const float* __restrict__ res,
                                              float* __restrict__ out,
                                              int Cin, int catOff,
                                              size_t in_bstr, size_t cat_bstr,
                                              int Cout) {
  int n = blockIdx.x * 256 + threadIdx.x;
  int o0 = blockIdx.y * 8;
  int z = blockIdx.z;           // s*B + b
  int s = z >> 2, b = z & 3;
  const float* ip = (s ? in1 : in0) + (size_t)b * in_bstr;
  const float* w0 = w + (size_t)o0 * Cin;
  float a[8];
#pragma unroll
  for (int i = 0; i < 8; ++i) a[i] = bias[o0 + i];
#pragma unroll 2
  for (int c = 0; c < catOff; ++c) {
    float v = ip[(size_t)c * N + n];
#pragma unroll
    for (int i = 0; i < 8; ++i) a[i] = fmaf(w0[i * Cin + c], v, a[i]);
  }
  if (cat0) {
    const float* cp = (s ? cat1 : cat0) + (size_t)b * cat_bstr;
#pragma unroll 2
    for (int c = catOff; c < Cin; ++c) {
      float v = cp[(size_t)(c - catOff) * N + n];
#pragma unroll
      for (int i = 0; i < 8; ++i) a[i] = fmaf(w0[i * Cin + c], v, a[i]);
    }
  }
  size_t ob = ((size_t)z * Cout + o0) * N + n;
  if (res) {
#pragma unroll
    for (int i = 0; i < 8; ++i) a[i] += res[ob + (size_t)i * N];
  }
#pragma unroll
  for (int i = 0; i < 8; ++i) out[ob + (size_t)i * N] = a[i];
}

// ---------------------------------------------------------------- attention v4
// grid (N/128, NH, 2*B), 256 thr = 4 waves. Wave s owns keys [s*256,(s+1)*256).
// Each lane owns TWO queries (lq, lq+64). K/V chunks of 32 keys staged per-wave
// in a SINGLE buffer (linear [64 rows][32] layout, contiguous float4 writes);
// NO barriers in the K-loop (wave-local LDS ordering). No prefetch regs, and
// softmax groups of 8 keys -> register budget ~170 (no scratch spill).
__global__ __launch_bounds__(256, 2) void k_attn(const float* __restrict__ Q,
                                                 const float* __restrict__ Kt,
                                                 const float* __restrict__ Vt,
                                                 float* __restrict__ O) {
  __shared__ float pool[16896];          // staging 4*2048; merge 4*128*33
  __shared__ float ms_[4][128], ls_[4][128];
  const int t  = threadIdx.x;
  const int lq = t & 63, s = t >> 6;
  const int q0 = blockIdx.x * 128;
  const int h  = blockIdx.y;
  const int z  = blockIdx.z;
  const size_t base = (size_t)z * (size_t)(D * N);
  const float* Kb = Kt + base;
  const float* Vb = Vt + base;
  const int sb    = s * 2048;           // per-wave staging region (single buf)
  const int wrow  = lq >> 3;            // 0..7
  const int wslot = (lq & 7) * 4;       // 0,4,..28

  float qA[32], qB[32], accA[32], accB[32];
#pragma unroll
  for (int d = 0; d < 32; ++d) {
    qA[d] = Q[base + (size_t)(d * 4 + h) * N + q0 + lq];
    qB[d] = Q[base + (size_t)(d * 4 + h) * N + q0 + 64 + lq];
    accA[d] = 0.f; accB[d] = 0.f;
  }
  float mxA = -1e30f, mxB = -1e30f, lA = 0.f, lB = 0.f;
  const float scale = 0.17677669529663687f;  // 1/sqrt(32)

  for (int c = 0; c < 8; ++c) {
    const int k0 = s * 256 + c * 32;
    // stage 32 keys x (32 K-dims + 32 V-dims), contiguous writes, wave-local
#pragma unroll
    for (int it = 0; it < 8; ++it) {
      int row = it * 8 + wrow;
      const float* src = (row < 32) ? (Kb + (size_t)(row * 4 + h) * N)
                                    : (Vb + (size_t)((row - 32) * 4 + h) * N);
      *(float4*)&pool[sb + row * 32 + wslot] = *(const float4*)(src + k0 + wslot);
    }
#pragma unroll
    for (int grp = 0; grp < 4; ++grp) {
      float scA[8], scB[8];
#pragma unroll
      for (int jg = 0; jg < 2; ++jg) {
        const int j0 = grp * 8 + jg * 4;
        float a0 = 0, a1 = 0, a2 = 0, a3 = 0, b0 = 0, b1 = 0, b2 = 0, b3 = 0;
#pragma unroll
        for (int d = 0; d < 32; ++d) {
          const float4 kv = *(const float4*)&pool[sb + d * 32 + j0];
          a0 = fmaf(qA[d], kv.x, a0); a1 = fmaf(qA[d], kv.y, a1);
          a2 = fmaf(qA[d], kv.z, a2); a3 = fmaf(qA[d], kv.w, a3);
          b0 = fmaf(qB[d], kv.x, b0); b1 = fmaf(qB[d], kv.y, b1);
          b2 = fmaf(qB[d], kv.z, b2); b3 = fmaf(qB[d], kv.w, b3);
        }
        scA[jg * 4 + 0] = a0 * scale; scA[jg * 4 + 1] = a1 * scale;
        scA[jg * 4 + 2] = a2 * scale; scA[jg * 4 + 3] = a3 * scale;
        scB[jg * 4 + 0] = b0 * scale; scB[jg * 4 + 1] = b1 * scale;
        scB[jg * 4 + 2] = b2 * scale; scB[jg * 4 + 3] = b3 * scale;
      }
      // online softmax over these 8 keys
      float hA = scA[0], hB = scB[0];
#pragma unroll
      for (int j = 1; j < 8; ++j) { hA = fmaxf(hA, scA[j]); hB = fmaxf(hB, scB[j]); }
      float nmA = fmaxf(mxA, hA), nmB = fmaxf(mxB, hB);
      float cA = __expf(mxA - nmA), cB = __expf(mxB - nmB);
      lA *= cA; lB *= cB;
#pragma unroll
      for (int d = 0; d < 32; ++d) { accA[d] *= cA; accB[d] *= cB; }
      mxA = nmA; mxB = nmB;
#pragma unroll
      for (int j = 0; j < 8; ++j) {
        scA[j] = __expf(scA[j] - mxA); lA += scA[j];
        scB[j] = __expf(scB[j] - mxB); lB += scB[j];
      }
      // PV
#pragma unroll
      for (int jg = 0; jg < 2; ++jg) {
        const int j0 = grp * 8 + jg * 4;
        float pa0 = scA[jg * 4 + 0], pa1 = scA[jg * 4 + 1];
        float pa2 = scA[jg * 4 + 2], pa3 = scA[jg * 4 + 3];
        float pb0 = scB[jg * 4 + 0], pb1 = scB[jg * 4 + 1];
        float pb2 = scB[jg * 4 + 2], pb3 = scB[jg * 4 + 3];
#pragma unroll
        for (int d = 0; d < 32; ++d) {
          const float4 v = *(const float4*)&pool[sb + (32 + d) * 32 + j0];
          accA[d] = fmaf(pa0, v.x, fmaf(pa1, v.y, fmaf(pa2, v.z, fmaf(pa3, v.w, accA[d]))));
          accB[d] = fmaf(pb0, v.x, fmaf(pb1, v.y, fmaf(pb2, v.z, fmaf(pb3, v.w, accB[d]))));
        }
      }
    }
  }

  // ---- merge 4 key-split partials
  ms_[s][lq] = mxA; ms_[s][64 + lq] = mxB;
  ls_[s][lq] = lA;  ls_[s][64 + lq] = lB;
  __syncthreads();                       // all staging reads done; reuse pool
#pragma unroll
  for (int d = 0; d < 32; ++d) {
    pool[(s * 128 + lq) * 33 + d] = accA[d];
    pool[(s * 128 + 64 + lq) * 33 + d] = accB[d];
  }
  __syncthreads();
  {
    int qq = t & 127, dh = t >> 7;
    float M = fmaxf(fmaxf(ms_[0][qq], ms_[1][qq]), fmaxf(ms_[2][qq], ms_[3][qq]));
    float wg[4], L = 0.f;
#pragma unroll
    for (int ss = 0; ss < 4; ++ss) {
      wg[ss] = __expf(ms_[ss][qq] - M);
      L += ls_[ss][qq] * wg[ss];
    }
    float invL = 1.f / L;
#pragma unroll
    for (int k = 0; k < 16; ++k) {
      int d = dh * 16 + k;
      float o = 0.f;
#pragma unroll
      for (int ss = 0; ss < 4; ++ss) o += pool[(ss * 128 + qq) * 33 + d] * wg[ss];
      O[base + (size_t)(d * 4 + h) * N + q0 + qq] = o * invL;
    }
  }
}

// ---------------------------------------------------------------- BN stats
__global__ __launch_bounds__(256) void k_bnstat(const float* __restrict__ h,
                                                float* __restrict__ stat) {
  int c = blockIdx.x, s = blockIdx.y, t = threadIdx.x;
  __shared__ float red[256];
  const float* base = h + ((size_t)s * B * 256 + c) * N;
  float sum = 0;
  for (int b = 0; b < B; ++b)
    for (int i = t; i < N; i += 256) sum += base[(size_t)b * 256 * N + i];
  red[t] = sum; __syncthreads();
  for (int sft = 128; sft > 0; sft >>= 1) {
    if (t < sft) red[t] += red[t + sft];
    __syncthreads();
  }
  float mean = red[0] / (float)(B * N);
  __syncthreads();
  float vs = 0;
  for (int b = 0; b < B; ++b)
    for (int i = t; i < N; i += 256) {
      float d = base[(size_t)b * 256 * N + i] - mean;
      vs += d * d;
    }
  red[t] = vs; __syncthreads();
  for (int sft = 128; sft > 0; sft >>= 1) {
    if (t < sft) red[t] += red[t + sft];
    __syncthreads();
  }
  if (t == 0) {
    float var = red[0] / (float)(B * N);
    stat[(s * 256 + c) * 2 + 0] = mean;
    stat[(s * 256 + c) * 2 + 1] = 1.f / sqrtf(var + 1e-5f);
  }
}

// ---------------------------------------------------------------- BN apply + relu
__global__ __launch_bounds__(256) void k_bnrelu(float* __restrict__ h,
                                                const float* __restrict__ stat,
                                                const float* __restrict__ g,
                                                const float* __restrict__ bt) {
  int i = blockIdx.x * 256 + threadIdx.x;
  int c = (i / N) % 256;
  int s = i / (B * 256 * N);
  float m = stat[(s * 256 + c) * 2 + 0];
  float is = stat[(s * 256 + c) * 2 + 1];
  float v = (h[i] - m) * is * g[c] + bt[c];
  h[i] = v > 0.f ? v : 0.f;
}

// ---------------------------------------------------------------- pairwise dist (8-m tile)
__global__ __launch_bounds__(256) void k_dist(const float* __restrict__ d0,
                                              const float* __restrict__ d1,
                                              float* __restrict__ la) {
  __shared__ float xm[8][128];
  __shared__ float n0s[8];
  int m0 = blockIdx.x * 8, b = blockIdx.y, t = threadIdx.x;
  const float* p0 = d0 + (size_t)b * D * N;
  const float* p1 = d1 + (size_t)b * D * N;
  for (int i = t; i < 8 * 128; i += 256) {
    int mm = i >> 7, d = i & 127;
    xm[mm][d] = p0[(size_t)d * N + m0 + mm];
  }
  __syncthreads();
  if (t < 8) {
    float s = 0;
    for (int d = 0; d < 128; ++d) s += xm[t][d] * xm[t][d];
    n0s[t] = s;
  }
  __syncthreads();
  float dot[8][4] = {{0}};
  float n1[4] = {0, 0, 0, 0};
  for (int d = 0; d < 128; ++d) {
    float v[4];
#pragma unroll
    for (int u = 0; u < 4; ++u) {
      v[u] = p1[(size_t)d * N + t + u * 256];
      n1[u] = fmaf(v[u], v[u], n1[u]);
    }
#pragma unroll
    for (int mm = 0; mm < 8; ++mm) {
      float x = xm[mm][d];
#pragma unroll
      for (int u = 0; u < 4; ++u) dot[mm][u] = fmaf(x, v[u], dot[mm][u]);
    }
  }
  for (int mm = 0; mm < 8; ++mm) {
    float* row = la + ((size_t)b * N + m0 + mm) * N;
#pragma unroll
    for (int u = 0; u < 4; ++u) {
      float dist2 = fmaxf(n0s[mm] + n1[u] - 2.f * dot[mm][u], 1e-30f);
      row[t + u * 256] = -sqrtf(dist2);
    }
  }
}

// ---------------------------------------------------------------- sinkhorn row (+ pending col sub)
__global__ __launch_bounds__(256) void k_row_lse(float* __restrict__ la,
                                                 const float* __restrict__ colse) {
  __shared__ float red[256];
  int t = threadIdx.x;
  int bm = blockIdx.x;              // over B*N
  int b = bm >> 10;
  float* row = la + (size_t)bm * N;
  float v0 = row[t], v1 = row[t + 256], v2 = row[t + 512], v3 = row[t + 768];
  if (colse) {
    const float* cl = colse + (size_t)b * N;
    v0 -= cl[t]; v1 -= cl[t + 256]; v2 -= cl[t + 512]; v3 -= cl[t + 768];
  }
  float mx = fmaxf(fmaxf(v0, v1), fmaxf(v2, v3));
  red[t] = mx; __syncthreads();
  for (int s = 128; s > 0; s >>= 1) {
    if (t < s) red[t] = fmaxf(red[t], red[t + s]);
    __syncthreads();
  }
  mx = red[0]; __syncthreads();
  float se = __expf(v0 - mx) + __expf(v1 - mx) + __expf(v2 - mx) + __expf(v3 - mx);
  red[t] = se; __syncthreads();
  for (int s = 128; s > 0; s >>= 1) {
    if (t < s) red[t] += red[t + s];
    __syncthreads();
  }
  float lse = mx + __logf(red[0]);
  row[t] = v0 - lse; row[t + 256] = v1 - lse;
  row[t + 512] = v2 - lse; row[t + 768] = v3 - lse;
}

// ---------------------------------------------------------------- sinkhorn col
__global__ __launch_bounds__(256) void k_col_part(const float* __restrict__ la,
                                                  float* __restrict__ pmax,
                                                  float* __restrict__ psum) {
  int t = threadIdx.x;
  int n = blockIdx.x * 256 + t;
  int p = blockIdx.y, b = blockIdx.z;
  const float* base = la + ((size_t)b * N + p * 128) * N + n;
  float mx = -1e30f, s = 0;
  for (int m = 0; m < 128; ++m) {
    float v = base[(size_t)m * N];
    if (v > mx) { s = s * __expf(mx - v) + 1.f; mx = v; }
    else s += __expf(v - mx);
  }
  pmax[((size_t)b * 8 + p) * N + n] = mx;
  psum[((size_t)b * 8 + p) * N + n] = s;
}

__global__ __launch_bounds__(256) void k_col_fin(const float* __restrict__ pmax,
                                                 const float* __restrict__ psum,
                                                 float* __restrict__ lse) {
  int i = blockIdx.x * 256 + threadIdx.x;  // over B*N
  int b = i / N, n = i % N;
  float mx = -1e30f;
  for (int p = 0; p < 8; ++p) mx = fmaxf(mx, pmax[((size_t)b * 8 + p) * N + n]);
  float s = 0;
  for (int p = 0; p < 8; ++p)
    s += psum[((size_t)b * 8 + p) * N + n] * __expf(pmax[((size_t)b * 8 + p) * N + n] - mx);
  lse[i] = mx + __logf(s);
}

// ---------------------------------------------------------------- rodrigues + transform
__global__ __launch_bounds__(256) void k_rod(const float* __restrict__ pose,
                                             const float* __restrict__ p3d,
                                             float* __restrict__ p3dt) {
  int b = blockIdx.y;
  int n = blockIdx.x * 256 + threadIdx.x;
  const float* aa = pose + b * 6;
  float ax = aa[0], ay = aa[1], az = aa[2];
  float th = fmaxf(sqrtf(ax * ax + ay * ay + az * az), 1e-8f);
  float rx = ax / th, ry = ay / th, rz = az / th;
  float c = cosf(th), s = sinf(th), oc = 1.f - c;
  float R00 = c + oc * rx * rx,      R01 = oc * rx * ry - s * rz, R02 = oc * rx * rz + s * ry;
  float R10 = oc * ry * rx + s * rz, R11 = c + oc * ry * ry,      R12 = oc * ry * rz - s * rx;
  float R20 = oc * rz * rx - s * ry, R21 = oc * rz * ry + s * rx, R22 = c + oc * rz * rz;
  const float* p = p3d + ((size_t)b * N + n) * 3;
  float x = p[0], y = p[1], z = p[2];
  float X = R00 * x + R01 * y + R02 * z + aa[3];
  float Y = R10 * x + R11 * y + R12 * z + aa[4];
  float Z = R20 * x + R21 * y + R22 * z + aa[5];
  float inr = 1.f / sqrtf(X * X + Y * Y + Z * Z);
  float* o = p3dt + ((size_t)b * N + n) * 3;
  o[0] = X * inr; o[1] = Y * inr; o[2] = Z * inr;
}

// ---------------------------------------------------------------- final error
__global__ __launch_bounds__(256) void k_err(const float* __restrict__ la,
                                             const float* __restrict__ colse,
                                             const float* __restrict__ f2,
                                             const float* __restrict__ p3dt,
                                             float* __restrict__ rowsum) {
  __shared__ float red[256];
  int m = blockIdx.x, b = blockIdx.y, t = threadIdx.x;
  const float* row = la + ((size_t)b * N + m) * N;
  const float* cl = colse + (size_t)b * N;
  const float* f = f2 + ((size_t)b * N + m) * 3;
  float fx = f[0], fy = f[1], fz = f[2];
  float s = 0;
  for (int n = t; n < N; n += 256) {
    const float* pp = p3dt + ((size_t)b * N + n) * 3;
    float dot = fx * pp[0] + fy * pp[1] + fz * pp[2];
    s += __expf(row[n] - cl[n]) * (1.f - dot);
  }
  red[t] = s; __syncthreads();
  for (int sft = 128; sft > 0; sft >>= 1) {
    if (t < sft) red[t] += red[t + sft];
    __syncthreads();
  }
  if (t == 0) rowsum[(size_t)b * N + m] = red[0];
}

__global__ __launch_bounds__(256) void k_err_fin(const float* __restrict__ rowsum,
                                                 float* __restrict__ out) {
  __shared__ float red[256];
  int b = blockIdx.x, t = threadIdx.x;
  float s = 0;
  for (int i = t; i < N; i += 256) s += rowsum[(size_t)b * N + i];
  red[t] = s; __syncthreads();
  for (int sft = 128; sft > 0; sft >>= 1) {
    if (t < sft) red[t] += red[t + sft];
    __syncthreads();
  }
  if (t == 0) out[b] = red[0];
}

// ================================================================= host
extern "C" void kernel_launch(void* const* d_in, const int* in_sizes, int n_in,
                              void* d_out, int out_size, void* d_ws, size_t ws_size,
                              hipStream_t stream) {
  const float* p2d     = (const float*)d_in[0];
  const float* p3d     = (const float*)d_in[1];
  const float* pose    = (const float*)d_in[2];
  const float* enc2d_w = (const float*)d_in[3];
  const float* enc2d_b = (const float*)d_in[4];
  const float* enc3d_w = (const float*)d_in[5];
  const float* enc3d_b = (const float*)d_in[6];
  const float* proj_w  = (const float*)d_in[7];
  const float* proj_b  = (const float*)d_in[8];
  const float* merge_w = (const float*)d_in[9];
  const float* merge_b = (const float*)d_in[10];
  const float* mlp1_w  = (const float*)d_in[11];
  const float* mlp1_b  = (const float*)d_in[12];
  const float* bn_g    = (const float*)d_in[13];
  const float* bn_b    = (const float*)d_in[14];
  const float* mlp2_w  = (const float*)d_in[15];
  const float* mlp2_b  = (const float*)d_in[16];

  float* W = (float*)d_ws;
  size_t off = 0;
  auto alloc = [&](size_t nelem) { float* p = W + off; off += nelem; return p; };
  const size_t SET = (size_t)B * D * N;
  float* f2    = alloc((size_t)B * N * 3);
  float* p3dt  = alloc((size_t)B * N * 3);
  float* descA = alloc(2 * SET);
  float* descB = alloc(2 * SET);
  float* Qb    = alloc(2 * SET);
  float* Kb    = alloc(2 * SET);
  float* Vb    = alloc(2 * SET);
  float* attnb = alloc(2 * SET);
  float* msgb  = alloc(2 * SET);
  float* hb    = alloc((size_t)2 * B * 256 * N);
  float* stat  = alloc(2 * 256 * 2);
  float* la    = alloc((size_t)B * N * N);
  float* pmax  = alloc((size_t)B * 8 * N);
  float* psum  = alloc((size_t)B * 8 * N);
  float* lseb  = alloc((size_t)B * N);
  float* rowsum= alloc((size_t)B * N);
  (void)ws_size; (void)in_sizes; (void)n_in; (void)out_size;

  auto conv = [&](const float* in0, const float* in1, const float* cat0,
                  const float* cat1, const float* w, const float* bias,
                  const float* res, float* out, int Cin, int catOff,
                  size_t in_bstr, size_t cat_bstr, int Cout) {
    dim3 g(N / 256, Cout / 8, 2 * B);
    k_conv<<<g, 256, 0, stream>>>(in0, in1, cat0, cat1, w, bias, res, out,
                                  Cin, catOff, in_bstr, cat_bstr, Cout);
  };

  k_norm2d<<<(B * N) / 256, 256, 0, stream>>>(p2d, f2);
  k_encode<<<dim3(N, B), 256, 0, stream>>>(f2, enc2d_w, enc2d_b, descA);
  k_encode<<<dim3(N, B), 256, 0, stream>>>(p3d, enc3d_w, enc3d_b, descA + SET);

  float* dc = descA;
  float* dn = descB;
  for (int i = 0; i < 6; ++i) {
    bool cross = (i & 1);
    const float* pw = proj_w + (size_t)i * 3 * D * D;
    const float* pb = proj_b + (size_t)i * 3 * D;
    float* d0 = dc;
    float* d1 = dc + SET;
    const float* sA = cross ? d1 : d0;
    const float* sB = cross ? d0 : d1;
    conv(d0, d1, nullptr, nullptr, pw,             pb,         nullptr, Qb, D, D, (size_t)D * N, 0, D);
    conv(sA, sB, nullptr, nullptr, pw + D * D,     pb + D,     nullptr, Kb, D, D, (size_t)D * N, 0, D);
    conv(sA, sB, nullptr, nullptr, pw + 2 * D * D, pb + 2 * D, nullptr, Vb, D, D, (size_t)D * N, 0, D);
    k_attn<<<dim3(N / 128, NH, 2 * B), 256, 0, stream>>>(Qb, Kb, Vb, attnb);
    conv(attnb, attnb + SET, nullptr, nullptr, merge_w + (size_t)i * D * D,
         merge_b + (size_t)i * D, nullptr, msgb, D, D, (size_t)D * N, 0, D);
    conv(d0, d1, msgb, msgb + SET, mlp1_w + (size_t)i * 256 * 256,
         mlp1_b + (size_t)i * 256, nullptr, hb, 256, 128, (size_t)D * N,
         (size_t)D * N, 256);
    k_bnstat<<<dim3(256, 2), 256, 0, stream>>>(hb, stat);
    k_bnrelu<<<(2 * B * 256 * N) / 256, 256, 0, stream>>>(
        hb, stat, bn_g + (size_t)i * 256, bn_b + (size_t)i * 256);
    conv(hb, hb + (size_t)B * 256 * N, nullptr, nullptr,
         mlp2_w + (size_t)i * D * 256, mlp2_b + (size_t)i * D, dc, dn, 256, 256,
         (size_t)256 * N, 0, D);
    float* tmp = dc; dc = dn; dn = tmp;
  }

  k_dist<<<dim3(N / 8, B), 256, 0, stream>>>(dc, dc + SET, la);
  for (int it = 0; it < 10; ++it) {
    k_row_lse<<<B * N, 256, 0, stream>>>(la, it == 0 ? nullptr : lseb);
    k_col_part<<<dim3(N / 256, 8, B), 256, 0, stream>>>(la, pmax, psum);
    k_col_fin<<<(B * N) / 256, 256, 0, stream>>>(pmax, psum, lseb);
  }
  k_rod<<<dim3(N / 256, B), 256, 0, stream>>>(pose, p3d, p3dt);
  k_err<<<dim3(N, B), 256, 0, stream>>>(la, lseb, f2, p3dt, rowsum);
  k_err_fin<<<B, 256, 0, stream>>>(rowsum, (float*)d_out);
}

// Round 5
// 2544.073 us; speedup vs baseline: 6.0619x; 1.8583x over previous
//
#include <hip/hip_runtime.h>
#include <hip/hip_bf16.h>

constexpr int B   = 4;
constexpr int N   = 1024;
constexpr int D   = 128;
constexpr int KNN = 10;
constexpr int NH  = 4;

// ---------------------------------------------------------------- norm p2d
__global__ __launch_bounds__(256) void k_norm2d(const float* __restrict__ p2d,
                                                float* __restrict__ f2) {
  int i = blockIdx.x * 256 + threadIdx.x;  // over B*N
  const float* p = p2d + (size_t)i * 3;
  float x = p[0], y = p[1], z = p[2];
  float inr = 1.f / sqrtf(x * x + y * y + z * z);
  float* o = f2 + (size_t)i * 3;
  o[0] = x * inr; o[1] = y * inr; o[2] = z * inr;
}

// ---------------------------------------------------------------- KNN encode
__global__ __launch_bounds__(256) void k_encode(const float* __restrict__ pts,
                                                const float* __restrict__ w,
                                                const float* __restrict__ bias,
                                                float* __restrict__ desc) {
  __shared__ float P[N][3];
  __shared__ float xx[N];
  __shared__ float dist[N];
  __shared__ float rv[256];
  __shared__ int   ri[256];
  __shared__ float feat[6];
  __shared__ int   nidx[KNN];
  int t = threadIdx.x;
  int n = blockIdx.x, b = blockIdx.y;
  const float* pb = pts + (size_t)b * N * 3;
  for (int i = t; i < N; i += 256) {
    float x = pb[i * 3 + 0], y = pb[i * 3 + 1], z = pb[i * 3 + 2];
    P[i][0] = x; P[i][1] = y; P[i][2] = z;
    xx[i] = x * x + y * y + z * z;
  }
  __syncthreads();
  float cx = P[n][0], cy = P[n][1], cz = P[n][2], cxx = xx[n];
  for (int i = t; i < N; i += 256) {
    float ip = cx * P[i][0] + cy * P[i][1] + cz * P[i][2];
    dist[i] = 2.f * ip - cxx - xx[i];
  }
  __syncthreads();
  for (int kk = 0; kk < KNN; ++kk) {
    float bv = -3.0e38f; int bi = N;
    for (int i = t; i < N; i += 256) {
      float v = dist[i];
      if (v > bv) { bv = v; bi = i; }
    }
    rv[t] = bv; ri[t] = bi;
    __syncthreads();
    for (int s = 128; s > 0; s >>= 1) {
      if (t < s) {
        float v2 = rv[t + s]; int i2 = ri[t + s];
        if (v2 > rv[t] || (v2 == rv[t] && i2 < ri[t])) { rv[t] = v2; ri[t] = i2; }
      }
      __syncthreads();
    }
    if (t == 0) { nidx[kk] = ri[0]; dist[ri[0]] = -3.0e38f; }
    __syncthreads();
  }
  if (t == 0) {
    float sx = 0, sy = 0, sz = 0;
    for (int kk = 0; kk < KNN; ++kk) {
      int i = nidx[kk];
      sx += P[i][0]; sy += P[i][1]; sz += P[i][2];
    }
    const float invk = 1.f / KNN;
    feat[0] = sx * invk - cx; feat[1] = sy * invk - cy; feat[2] = sz * invk - cz;
    feat[3] = cx; feat[4] = cy; feat[5] = cz;
  }
  __syncthreads();
  if (t < D) {
    const float* wr = w + t * 6;
    float a = bias[t];
#pragma unroll
    for (int j = 0; j < 6; ++j) a += wr[j] * feat[j];
    desc[((size_t)b * D + t) * N + n] = a;
  }
}

// ---------------------------------------------------------------- generic conv1 (8-o unroll)
// grid (N/256, Cout/8, 2*B)
__global__ __launch_bounds__(256) void k_conv(const float* __restrict__ in0,
                                              const float* __restrict__ in1,
                                              const float* __restrict__ cat0,
                                              const float* __restrict__ cat1,
                                              const float* __restrict__ w,
                                              const float* __restrict__ bias,
                                              const float* __restrict__ res,
                                              float* __restrict__ out,
                                              int Cin, int catOff,
                                              size_t in_bstr, size_t cat_bstr,
                                              int Cout) {
  int n = blockIdx.x * 256 + threadIdx.x;
  int o0 = blockIdx.y * 8;
  int z = blockIdx.z;           // s*B + b
  int s = z >> 2, b = z & 3;
  const float* ip = (s ? in1 : in0) + (size_t)b * in_bstr;
  const float* w0 = w + (size_t)o0 * Cin;
  float a[8];
#pragma unroll
  for (int i = 0; i < 8; ++i) a[i] = bias[o0 + i];
#pragma unroll 2
  for (int c = 0; c < catOff; ++c) {
    float v = ip[(size_t)c * N + n];
#pragma unroll
    for (int i = 0; i < 8; ++i) a[i] = fmaf(w0[i * Cin + c], v, a[i]);
  }
  if (cat0) {
    const float* cp = (s ? cat1 : cat0) + (size_t)b * cat_bstr;
#pragma unroll 2
    for (int c = catOff; c < Cin; ++c) {
      float v = cp[(size_t)(c - catOff) * N + n];
#pragma unroll
      for (int i = 0; i < 8; ++i) a[i] = fmaf(w0[i * Cin + c], v, a[i]);
    }
  }
  size_t ob = ((size_t)z * Cout + o0) * N + n;
  if (res) {
#pragma unroll
    for (int i = 0; i < 8; ++i) a[i] += res[ob + (size_t)i * N];
  }
#pragma unroll
  for (int i = 0; i < 8; ++i) out[ob + (size_t)i * N] = a[i];
}

// ---------------------------------------------------------------- attention v5
// grid (N/128, NH, 2*B), 256 thr = 4 waves. Wave s owns keys [s*256,(s+1)*256).
// Each lane owns TWO queries (lq, lq+64). K/V chunks of 32 keys staged per-wave
// in a SINGLE buffer; NO barriers in the K-loop (wave-local LDS ordering).
// NO min-waves bound: needs ~180 VGPR, must not be capped at 128 (R4 lesson:
// launch_bounds(256,2) forced 128 -> 488MB scratch spill traffic).
__global__ __launch_bounds__(256) void k_attn(const float* __restrict__ Q,
                                              const float* __restrict__ Kt,
                                              const float* __restrict__ Vt,
                                              float* __restrict__ O) {
  __shared__ float pool[16896];          // staging 4*2048; merge 4*128*33
  __shared__ float ms_[4][128], ls_[4][128];
  const int t  = threadIdx.x;
  const int lq = t & 63, s = t >> 6;
  const int q0 = blockIdx.x * 128;
  const int h  = blockIdx.y;
  const int z  = blockIdx.z;
  const size_t base = (size_t)z * (size_t)(D * N);
  const float* Kb = Kt + base;
  const float* Vb = Vt + base;
  const int sb    = s * 2048;           // per-wave staging region (single buf)
  const int wrow  = lq >> 3;            // 0..7
  const int wslot = (lq & 7) * 4;       // 0,4,..28

  const float scale = 0.17677669529663687f;  // 1/sqrt(32), folded into q
  float qA[32], qB[32], accA[32], accB[32];
#pragma unroll
  for (int d = 0; d < 32; ++d) {
    qA[d] = Q[base + (size_t)(d * 4 + h) * N + q0 + lq] * scale;
    qB[d] = Q[base + (size_t)(d * 4 + h) * N + q0 + 64 + lq] * scale;
    accA[d] = 0.f; accB[d] = 0.f;
  }
  float mxA = -1e30f, mxB = -1e30f, lA = 0.f, lB = 0.f;

  for (int c = 0; c < 8; ++c) {
    const int k0 = s * 256 + c * 32;
    // stage 32 keys x (32 K-dims + 32 V-dims), contiguous writes, wave-local
#pragma unroll
    for (int it = 0; it < 8; ++it) {
      int row = it * 8 + wrow;
      const float* src = (row < 32) ? (Kb + (size_t)(row * 4 + h) * N)
                                    : (Vb + (size_t)((row - 32) * 4 + h) * N);
      *(float4*)&pool[sb + row * 32 + wslot] = *(const float4*)(src + k0 + wslot);
    }
#pragma unroll
    for (int grp = 0; grp < 4; ++grp) {
      float scA[8], scB[8];
#pragma unroll
      for (int jg = 0; jg < 2; ++jg) {
        const int j0 = grp * 8 + jg * 4;
        float a0 = 0, a1 = 0, a2 = 0, a3 = 0, b0 = 0, b1 = 0, b2 = 0, b3 = 0;
#pragma unroll
        for (int d = 0; d < 32; ++d) {
          const float4 kv = *(const float4*)&pool[sb + d * 32 + j0];
          a0 = fmaf(qA[d], kv.x, a0); a1 = fmaf(qA[d], kv.y, a1);
          a2 = fmaf(qA[d], kv.z, a2); a3 = fmaf(qA[d], kv.w, a3);
          b0 = fmaf(qB[d], kv.x, b0); b1 = fmaf(qB[d], kv.y, b1);
          b2 = fmaf(qB[d], kv.z, b2); b3 = fmaf(qB[d], kv.w, b3);
        }
        scA[jg * 4 + 0] = a0; scA[jg * 4 + 1] = a1;
        scA[jg * 4 + 2] = a2; scA[jg * 4 + 3] = a3;
        scB[jg * 4 + 0] = b0; scB[jg * 4 + 1] = b1;
        scB[jg * 4 + 2] = b2; scB[jg * 4 + 3] = b3;
      }
      // online softmax over these 8 keys
      float hA = scA[0], hB = scB[0];
#pragma unroll
      for (int j = 1; j < 8; ++j) { hA = fmaxf(hA, scA[j]); hB = fmaxf(hB, scB[j]); }
      float nmA = fmaxf(mxA, hA), nmB = fmaxf(mxB, hB);
      float cA = __expf(mxA - nmA), cB = __expf(mxB - nmB);
      lA *= cA; lB *= cB;
#pragma unroll
      for (int d = 0; d < 32; ++d) { accA[d] *= cA; accB[d] *= cB; }
      mxA = nmA; mxB = nmB;
#pragma unroll
      for (int j = 0; j < 8; ++j) {
        scA[j] = __expf(scA[j] - mxA); lA += scA[j];
        scB[j] = __expf(scB[j] - mxB); lB += scB[j];
      }
      // PV
#pragma unroll
      for (int jg = 0; jg < 2; ++jg) {
        const int j0 = grp * 8 + jg * 4;
        float pa0 = scA[jg * 4 + 0], pa1 = scA[jg * 4 + 1];
        float pa2 = scA[jg * 4 + 2], pa3 = scA[jg * 4 + 3];
        float pb0 = scB[jg * 4 + 0], pb1 = scB[jg * 4 + 1];
        float pb2 = scB[jg * 4 + 2], pb3 = scB[jg * 4 + 3];
#pragma unroll
        for (int d = 0; d < 32; ++d) {
          const float4 v = *(const float4*)&pool[sb + (32 + d) * 32 + j0];
          accA[d] = fmaf(pa0, v.x, fmaf(pa1, v.y, fmaf(pa2, v.z, fmaf(pa3, v.w, accA[d]))));
          accB[d] = fmaf(pb0, v.x, fmaf(pb1, v.y, fmaf(pb2, v.z, fmaf(pb3, v.w, accB[d]))));
        }
      }
    }
  }

  // ---- merge 4 key-split partials
  ms_[s][lq] = mxA; ms_[s][64 + lq] = mxB;
  ls_[s][lq] = lA;  ls_[s][64 + lq] = lB;
  __syncthreads();                       // all staging reads done; reuse pool
#pragma unroll
  for (int d = 0; d < 32; ++d) {
    pool[(s * 128 + lq) * 33 + d] = accA[d];
    pool[(s * 128 + 64 + lq) * 33 + d] = accB[d];
  }
  __syncthreads();
  {
    int qq = t & 127, dh = t >> 7;
    float M = fmaxf(fmaxf(ms_[0][qq], ms_[1][qq]), fmaxf(ms_[2][qq], ms_[3][qq]));
    float wg[4], L = 0.f;
#pragma unroll
    for (int ss = 0; ss < 4; ++ss) {
      wg[ss] = __expf(ms_[ss][qq] - M);
      L += ls_[ss][qq] * wg[ss];
    }
    float invL = 1.f / L;
#pragma unroll
    for (int k = 0; k < 16; ++k) {
      int d = dh * 16 + k;
      float o = 0.f;
#pragma unroll
      for (int ss = 0; ss < 4; ++ss) o += pool[(ss * 128 + qq) * 33 + d] * wg[ss];
      O[base + (size_t)(d * 4 + h) * N + q0 + qq] = o * invL;
    }
  }
}

// ---------------------------------------------------------------- BN stats
__global__ __launch_bounds__(256) void k_bnstat(const float* __restrict__ h,
                                                float* __restrict__ stat) {
  int c = blockIdx.x, s = blockIdx.y, t = threadIdx.x;
  __shared__ float red[256];
  const float* base = h + ((size_t)s * B * 256 + c) * N;
  float sum = 0;
  for (int b = 0; b < B; ++b)
    for (int i = t; i < N; i += 256) sum += base[(size_t)b * 256 * N + i];
  red[t] = sum; __syncthreads();
  for (int sft = 128; sft > 0; sft >>= 1) {
    if (t < sft) red[t] += red[t + sft];
    __syncthreads();
  }
  float mean = red[0] / (float)(B * N);
  __syncthreads();
  float vs = 0;
  for (int b = 0; b < B; ++b)
    for (int i = t; i < N; i += 256) {
      float d = base[(size_t)b * 256 * N + i] - mean;
      vs += d * d;
    }
  red[t] = vs; __syncthreads();
  for (int sft = 128; sft > 0; sft >>= 1) {
    if (t < sft) red[t] += red[t + sft];
    __syncthreads();
  }
  if (t == 0) {
    float var = red[0] / (float)(B * N);
    stat[(s * 256 + c) * 2 + 0] = mean;
    stat[(s * 256 + c) * 2 + 1] = 1.f / sqrtf(var + 1e-5f);
  }
}

// ---------------------------------------------------------------- BN apply + relu
__global__ __launch_bounds__(256) void k_bnrelu(float* __restrict__ h,
                                                const float* __restrict__ stat,
                                                const float* __restrict__ g,
                                                const float* __restrict__ bt) {
  int i = blockIdx.x * 256 + threadIdx.x;
  int c = (i / N) % 256;
  int s = i / (B * 256 * N);
  float m = stat[(s * 256 + c) * 2 + 0];
  float is = stat[(s * 256 + c) * 2 + 1];
  float v = (h[i] - m) * is * g[c] + bt[c];
  h[i] = v > 0.f ? v : 0.f;
}

// ---------------------------------------------------------------- pairwise dist (8-m tile)
__global__ __launch_bounds__(256) void k_dist(const float* __restrict__ d0,
                                              const float* __restrict__ d1,
                                              float* __restrict__ la) {
  __shared__ float xm[8][128];
  __shared__ float n0s[8];
  int m0 = blockIdx.x * 8, b = blockIdx.y, t = threadIdx.x;
  const float* p0 = d0 + (size_t)b * D * N;
  const float* p1 = d1 + (size_t)b * D * N;
  for (int i = t; i < 8 * 128; i += 256) {
    int mm = i >> 7, d = i & 127;
    xm[mm][d] = p0[(size_t)d * N + m0 + mm];
  }
  __syncthreads();
  if (t < 8) {
    float s = 0;
    for (int d = 0; d < 128; ++d) s += xm[t][d] * xm[t][d];
    n0s[t] = s;
  }
  __syncthreads();
  float dot[8][4] = {{0}};
  float n1[4] = {0, 0, 0, 0};
  for (int d = 0; d < 128; ++d) {
    float v[4];
#pragma unroll
    for (int u = 0; u < 4; ++u) {
      v[u] = p1[(size_t)d * N + t + u * 256];
      n1[u] = fmaf(v[u], v[u], n1[u]);
    }
#pragma unroll
    for (int mm = 0; mm < 8; ++mm) {
      float x = xm[mm][d];
#pragma unroll
      for (int u = 0; u < 4; ++u) dot[mm][u] = fmaf(x, v[u], dot[mm][u]);
    }
  }
  for (int mm = 0; mm < 8; ++mm) {
    float* row = la + ((size_t)b * N + m0 + mm) * N;
#pragma unroll
    for (int u = 0; u < 4; ++u) {
      float dist2 = fmaxf(n0s[mm] + n1[u] - 2.f * dot[mm][u], 1e-30f);
      row[t + u * 256] = -sqrtf(dist2);
    }
  }
}

// ---------------------------------------------------------------- sinkhorn row (+ pending col sub)
__global__ __launch_bounds__(256) void k_row_lse(float* __restrict__ la,
                                                 const float* __restrict__ colse) {
  __shared__ float red[256];
  int t = threadIdx.x;
  int bm = blockIdx.x;              // over B*N
  int b = bm >> 10;
  float* row = la + (size_t)bm * N;
  float v0 = row[t], v1 = row[t + 256], v2 = row[t + 512], v3 = row[t + 768];
  if (colse) {
    const float* cl = colse + (size_t)b * N;
    v0 -= cl[t]; v1 -= cl[t + 256]; v2 -= cl[t + 512]; v3 -= cl[t + 768];
  }
  float mx = fmaxf(fmaxf(v0, v1), fmaxf(v2, v3));
  red[t] = mx; __syncthreads();
  for (int s = 128; s > 0; s >>= 1) {
    if (t < s) red[t] = fmaxf(red[t], red[t + s]);
    __syncthreads();
  }
  mx = red[0]; __syncthreads();
  float se = __expf(v0 - mx) + __expf(v1 - mx) + __expf(v2 - mx) + __expf(v3 - mx);
  red[t] = se; __syncthreads();
  for (int s = 128; s > 0; s >>= 1) {
    if (t < s) red[t] += red[t + s];
    __syncthreads();
  }
  float lse = mx + __logf(red[0]);
  row[t] = v0 - lse; row[t + 256] = v1 - lse;
  row[t + 512] = v2 - lse; row[t + 768] = v3 - lse;
}

// ---------------------------------------------------------------- sinkhorn col
__global__ __launch_bounds__(256) void k_col_part(const float* __restrict__ la,
                                                  float* __restrict__ pmax,
                                                  float* __restrict__ psum) {
  int t = threadIdx.x;
  int n = blockIdx.x * 256 + t;
  int p = blockIdx.y, b = blockIdx.z;
  const float* base = la + ((size_t)b * N + p * 128) * N + n;
  float mx = -1e30f, s = 0;
  for (int m = 0; m < 128; ++m) {
    float v = base[(size_t)m * N];
    if (v > mx) { s = s * __expf(mx - v) + 1.f; mx = v; }
    else s += __expf(v - mx);
  }
  pmax[((size_t)b * 8 + p) * N + n] = mx;
  psum[((size_t)b * 8 + p) * N + n] = s;
}

__global__ __launch_bounds__(256) void k_col_fin(const float* __restrict__ pmax,
                                                 const float* __restrict__ psum,
                                                 float* __restrict__ lse) {
  int i = blockIdx.x * 256 + threadIdx.x;  // over B*N
  int b = i / N, n = i % N;
  float mx = -1e30f;
  for (int p = 0; p < 8; ++p) mx = fmaxf(mx, pmax[((size_t)b * 8 + p) * N + n]);
  float s = 0;
  for (int p = 0; p < 8; ++p)
    s += psum[((size_t)b * 8 + p) * N + n] * __expf(pmax[((size_t)b * 8 + p) * N + n] - mx);
  lse[i] = mx + __logf(s);
}

// ---------------------------------------------------------------- rodrigues + transform
__global__ __launch_bounds__(256) void k_rod(const float* __restrict__ pose,
                                             const float* __restrict__ p3d,
                                             float* __restrict__ p3dt) {
  int b = blockIdx.y;
  int n = blockIdx.x * 256 + threadIdx.x;
  const float* aa = pose + b * 6;
  float ax = aa[0], ay = aa[1], az = aa[2];
  float th = fmaxf(sqrtf(ax * ax + ay * ay + az * az), 1e-8f);
  float rx = ax / th, ry = ay / th, rz = az / th;
  float c = cosf(th), s = sinf(th), oc = 1.f - c;
  float R00 = c + oc * rx * rx,      R01 = oc * rx * ry - s * rz, R02 = oc * rx * rz + s * ry;
  float R10 = oc * ry * rx + s * rz, R11 = c + oc * ry * ry,      R12 = oc * ry * rz - s * rx;
  float R20 = oc * rz * rx - s * ry, R21 = oc * rz * ry + s * rx, R22 = c + oc * rz * rz;
  const float* p = p3d + ((size_t)b * N + n) * 3;
  float x = p[0], y = p[1], z = p[2];
  float X = R00 * x + R01 * y + R02 * z + aa[3];
  float Y = R10 * x + R11 * y + R12 * z + aa[4];
  float Z = R20 * x + R21 * y + R22 * z + aa[5];
  float inr = 1.f / sqrtf(X * X + Y * Y + Z * Z);
  float* o = p3dt + ((size_t)b * N + n) * 3;
  o[0] = X * inr; o[1] = Y * inr; o[2] = Z * inr;
}

// ---------------------------------------------------------------- final error
__global__ __launch_bounds__(256) void k_err(const float* __restrict__ la,
                                             const float* __restrict__ colse,
                                             const float* __restrict__ f2,
                                             const float* __restrict__ p3dt,
                                             float* __restrict__ rowsum) {
  __shared__ float red[256];
  int m = blockIdx.x, b = blockIdx.y, t = threadIdx.x;
  const float* row = la + ((size_t)b * N + m) * N;
  const float* cl = colse + (size_t)b * N;
  const float* f = f2 + ((size_t)b * N + m) * 3;
  float fx = f[0], fy = f[1], fz = f[2];
  float s = 0;
  for (int n = t; n < N; n += 256) {
    const float* pp = p3dt + ((size_t)b * N + n) * 3;
    float dot = fx * pp[0] + fy * pp[1] + fz * pp[2];
    s += __expf(row[n] - cl[n]) * (1.f - dot);
  }
  red[t] = s; __syncthreads();
  for (int sft = 128; sft > 0; sft >>= 1) {
    if (t < sft) red[t] += red[t + sft];
    __syncthreads();
  }
  if (t == 0) rowsum[(size_t)b * N + m] = red[0];
}

__global__ __launch_bounds__(256) void k_err_fin(const float* __restrict__ rowsum,
                                                 float* __restrict__ out) {
  __shared__ float red[256];
  int b = blockIdx.x, t = threadIdx.x;
  float s = 0;
  for (int i = t; i < N; i += 256) s += rowsum[(size_t)b * N + i];
  red[t] = s; __syncthreads();
  for (int sft = 128; sft > 0; sft >>= 1) {
    if (t < sft) red[t] += red[t + sft];
    __syncthreads();
  }
  if (t == 0) out[b] = red[0];
}

// ================================================================= host
extern "C" void kernel_launch(void* const* d_in, const int* in_sizes, int n_in,
                              void* d_out, int out_size, void* d_ws, size_t ws_size,
                              hipStream_t stream) {
  const float* p2d     = (const float*)d_in[0];
  const float* p3d     = (const float*)d_in[1];
  const float* pose    = (const float*)d_in[2];
  const float* enc2d_w = (const float*)d_in[3];
  const float* enc2d_b = (const float*)d_in[4];
  const float* enc3d_w = (const float*)d_in[5];
  const float* enc3d_b = (const float*)d_in[6];
  const float* proj_w  = (const float*)d_in[7];
  const float* proj_b  = (const float*)d_in[8];
  const float* merge_w = (const float*)d_in[9];
  const float* merge_b = (const float*)d_in[10];
  const float* mlp1_w  = (const float*)d_in[11];
  const float* mlp1_b  = (const float*)d_in[12];
  const float* bn_g    = (const float*)d_in[13];
  const float* bn_b    = (const float*)d_in[14];
  const float* mlp2_w  = (const float*)d_in[15];
  const float* mlp2_b  = (const float*)d_in[16];

  float* W = (float*)d_ws;
  size_t off = 0;
  auto alloc = [&](size_t nelem) { float* p = W + off; off += nelem; return p; };
  const size_t SET = (size_t)B * D * N;
  float* f2    = alloc((size_t)B * N * 3);
  float* p3dt  = alloc((size_t)B * N * 3);
  float* descA = alloc(2 * SET);
  float* descB = alloc(2 * SET);
  float* Qb    = alloc(2 * SET);
  float* Kb    = alloc(2 * SET);
  float* Vb    = alloc(2 * SET);
  float* attnb = alloc(2 * SET);
  float* msgb  = alloc(2 * SET);
  float* hb    = alloc((size_t)2 * B * 256 * N);
  float* stat  = alloc(2 * 256 * 2);
  float* la    = alloc((size_t)B * N * N);
  float* pmax  = alloc((size_t)B * 8 * N);
  float* psum  = alloc((size_t)B * 8 * N);
  float* lseb  = alloc((size_t)B * N);
  float* rowsum= alloc((size_t)B * N);
  (void)ws_size; (void)in_sizes; (void)n_in; (void)out_size;

  auto conv = [&](const float* in0, const float* in1, const float* cat0,
                  const float* cat1, const float* w, const float* bias,
                  const float* res, float* out, int Cin, int catOff,
                  size_t in_bstr, size_t cat_bstr, int Cout) {
    dim3 g(N / 256, Cout / 8, 2 * B);
    k_conv<<<g, 256, 0, stream>>>(in0, in1, cat0, cat1, w, bias, res, out,
                                  Cin, catOff, in_bstr, cat_bstr, Cout);
  };

  k_norm2d<<<(B * N) / 256, 256, 0, stream>>>(p2d, f2);
  k_encode<<<dim3(N, B), 256, 0, stream>>>(f2, enc2d_w, enc2d_b, descA);
  k_encode<<<dim3(N, B), 256, 0, stream>>>(p3d, enc3d_w, enc3d_b, descA + SET);

  float* dc = descA;
  float* dn = descB;
  for (int i = 0; i < 6; ++i) {
    bool cross = (i & 1);
    const float* pw = proj_w + (size_t)i * 3 * D * D;
    const float* pb = proj_b + (size_t)i * 3 * D;
    float* d0 = dc;
    float* d1 = dc + SET;
    const float* sA = cross ? d1 : d0;
    const float* sB = cross ? d0 : d1;
    conv(d0, d1, nullptr, nullptr, pw,             pb,         nullptr, Qb, D, D, (size_t)D * N, 0, D);
    conv(sA, sB, nullptr, nullptr, pw + D * D,     pb + D,     nullptr, Kb, D, D, (size_t)D * N, 0, D);
    conv(sA, sB, nullptr, nullptr, pw + 2 * D * D, pb + 2 * D, nullptr, Vb, D, D, (size_t)D * N, 0, D);
    k_attn<<<dim3(N / 128, NH, 2 * B), 256, 0, stream>>>(Qb, Kb, Vb, attnb);
    conv(attnb, attnb + SET, nullptr, nullptr, merge_w + (size_t)i * D * D,
         merge_b + (size_t)i * D, nullptr, msgb, D, D, (size_t)D * N, 0, D);
    conv(d0, d1, msgb, msgb + SET, mlp1_w + (size_t)i * 256 * 256,
         mlp1_b + (size_t)i * 256, nullptr, hb, 256, 128, (size_t)D * N,
         (size_t)D * N, 256);
    k_bnstat<<<dim3(256, 2), 256, 0, stream>>>(hb, stat);
    k_bnrelu<<<(2 * B * 256 * N) / 256, 256, 0, stream>>>(
        hb, stat, bn_g + (size_t)i * 256, bn_b + (size_t)i * 256);
    conv(hb, hb + (size_t)B * 256 * N, nullptr, nullptr,
         mlp2_w + (size_t)i * D * 256, mlp2_b + (size_t)i * D, dc, dn, 256, 256,
         (size_t)256 * N, 0, D);
    float* tmp = dc; dc = dn; dn = tmp;
  }

  k_dist<<<dim3(N / 8, B), 256, 0, stream>>>(dc, dc + SET, la);
  for (int it = 0; it < 10; ++it) {
    k_row_lse<<<B * N, 256, 0, stream>>>(la, it == 0 ? nullptr : lseb);
    k_col_part<<<dim3(N / 256, 8, B), 256, 0, stream>>>(la, pmax, psum);
    k_col_fin<<<(B * N) / 256, 256, 0, stream>>>(pmax, psum, lseb);
  }
  k_rod<<<dim3(N / 256, B), 256, 0, stream>>>(pose, p3d, p3dt);
  k_err<<<dim3(N, B), 256, 0, stream>>>(la, lseb, f2, p3dt, rowsum);
  k_err_fin<<<B, 256, 0, stream>>>(rowsum, (float*)d_out);
}